// Round 1
// baseline (764.900 us; speedup 1.0000x reference)
//
#include <hip/hip_runtime.h>
#include <hip/hip_bf16.h>

// Problem constants
#define BATCH 4
#define SEQ   8192
#define DIM   512
#define M_TOT (BATCH*SEQ)   // 32768
#define NCHUNK 64
#define CLEN   128          // SEQ / NCHUNK

// GEMM tiling
#define TM 64
#define TN 64
#define BKK 32

__device__ __forceinline__ float sigmoidf_(float x) {
    return 1.0f / (1.0f + __expf(-x));
}

// g(x) = exp(log_g(x)) = x>=0 ? x+0.5 : sigmoid(x)
__device__ __forceinline__ float gfun_(float x) {
    return (x >= 0.0f) ? (x + 0.5f) : sigmoidf_(x);
}

// Computes, for each row r of x (M_TOT x DIM) and col n:
//   kf = x@Wf + bf ; ki = x@Wi + bi ; kh = x@Wh + bh
//   f = sigmoid(kf) ; v = sigmoid(ki) * g(kh)
__global__ __launch_bounds__(256) void gemm_gates(
    const float* __restrict__ x,
    const float* __restrict__ Wf, const float* __restrict__ bf,
    const float* __restrict__ Wi, const float* __restrict__ bi,
    const float* __restrict__ Wh, const float* __restrict__ bh,
    float* __restrict__ fbuf, float* __restrict__ vbuf)
{
    const int K = DIM, N = DIM;
    __shared__ float As[BKK][TM + 4];      // [k][m]
    __shared__ float Bs[3][BKK][TN + 4];   // [w][k][n]

    const int n0 = blockIdx.x * TN;
    const int m0 = blockIdx.y * TM;
    const int tid = threadIdx.x;
    const int tx = tid & 15;
    const int ty = tid >> 4;

    const float* Ws[3] = {Wf, Wi, Wh};
    float acc[3][4][4] = {};

    for (int k0 = 0; k0 < K; k0 += BKK) {
        // load A tile 64(m) x 32(k): 2 passes x 256 threads x float4
        {
            const int mrow = tid >> 3;   // 0..31
            const int kq   = tid & 7;    // float4 index along k
            #pragma unroll
            for (int p = 0; p < 2; ++p) {
                const int m = mrow + p * 32;
                float4 vv = *(const float4*)&x[(size_t)(m0 + m) * K + k0 + kq * 4];
                As[kq * 4 + 0][m] = vv.x;
                As[kq * 4 + 1][m] = vv.y;
                As[kq * 4 + 2][m] = vv.z;
                As[kq * 4 + 3][m] = vv.w;
            }
        }
        // load 3 B tiles 32(k) x 64(n)
        {
            const int krow = tid >> 4;   // 0..15
            const int nq   = tid & 15;   // float4 index along n
            #pragma unroll
            for (int w = 0; w < 3; ++w) {
                const float* W = Ws[w];
                #pragma unroll
                for (int p = 0; p < 2; ++p) {
                    const int kk = krow + p * 16;
                    float4 vv = *(const float4*)&W[(size_t)(k0 + kk) * N + n0 + nq * 4];
                    *(float4*)&Bs[w][kk][nq * 4] = vv;
                }
            }
        }
        __syncthreads();
        #pragma unroll
        for (int kk = 0; kk < BKK; ++kk) {
            float a[4];
            *(float4*)a = *(const float4*)&As[kk][ty * 4];
            #pragma unroll
            for (int w = 0; w < 3; ++w) {
                float b[4];
                *(float4*)b = *(const float4*)&Bs[w][kk][tx * 4];
                #pragma unroll
                for (int i = 0; i < 4; ++i)
                    #pragma unroll
                    for (int j = 0; j < 4; ++j)
                        acc[w][i][j] = fmaf(a[i], b[j], acc[w][i][j]);
            }
        }
        __syncthreads();
    }

    // epilogue: gate transforms, write f and v
    #pragma unroll
    for (int i = 0; i < 4; ++i) {
        const int r = m0 + ty * 4 + i;
        #pragma unroll
        for (int j = 0; j < 4; ++j) {
            const int n = n0 + tx * 4 + j;
            float kf = acc[0][i][j] + bf[n];
            float ki = acc[1][i][j] + bi[n];
            float kh = acc[2][i][j] + bh[n];
            float f = sigmoidf_(kf);
            float v = sigmoidf_(ki) * gfun_(kh);
            fbuf[(size_t)r * DIM + n] = f;
            vbuf[(size_t)r * DIM + n] = v;
        }
    }
}

// Pass 1: per (b, d, chunk) compute A = prod f, Bacc = local scan with h_in = 0
__global__ __launch_bounds__(256) void scan_pass1(
    const float* __restrict__ fbuf, const float* __restrict__ vbuf,
    float* __restrict__ Ach, float* __restrict__ Bch)
{
    const int d = blockIdx.x * 256 + threadIdx.x;  // 0..511 (grid.x = 2)
    const int c = blockIdx.y;                      // chunk
    const int b = blockIdx.z;                      // batch
    float A = 1.0f, Bacc = 0.0f;
    size_t base = ((size_t)(b * SEQ + c * CLEN)) * DIM + d;
    #pragma unroll 8
    for (int t = 0; t < CLEN; ++t) {
        float f = fbuf[base + (size_t)t * DIM];
        float v = vbuf[base + (size_t)t * DIM];
        Bacc = fmaf(f, Bacc, v);
        A *= f;
    }
    const int idx = (b * NCHUNK + c) * DIM + d;
    Ach[idx] = A;
    Bch[idx] = Bacc;
}

// Pass 2: sequential carry scan over chunks per (b, d); writes carry-IN per chunk
__global__ __launch_bounds__(256) void scan_pass2(
    const float* __restrict__ pre_h,
    const float* __restrict__ Ach, const float* __restrict__ Bch,
    float* __restrict__ carry)
{
    const int g = blockIdx.x * 256 + threadIdx.x;  // 0..2047
    const int b = g >> 9;
    const int d = g & (DIM - 1);
    float p = pre_h[b * DIM + d];
    float h = gfun_(p);   // h_0 = g(pre_h)
    for (int c = 0; c < NCHUNK; ++c) {
        const int idx = (b * NCHUNK + c) * DIM + d;
        carry[idx] = h;
        h = fmaf(Ach[idx], h, Bch[idx]);
    }
}

// Pass 3: apply carry, recompute local recurrence, emit h
__global__ __launch_bounds__(256) void scan_pass3(
    const float* __restrict__ fbuf, const float* __restrict__ vbuf,
    const float* __restrict__ carry, float* __restrict__ out)
{
    const int d = blockIdx.x * 256 + threadIdx.x;
    const int c = blockIdx.y;
    const int b = blockIdx.z;
    float h = carry[(b * NCHUNK + c) * DIM + d];
    size_t base = ((size_t)(b * SEQ + c * CLEN)) * DIM + d;
    #pragma unroll 8
    for (int t = 0; t < CLEN; ++t) {
        float f = fbuf[base + (size_t)t * DIM];
        float v = vbuf[base + (size_t)t * DIM];
        h = fmaf(f, h, v);
        out[base + (size_t)t * DIM] = h;
    }
}

extern "C" void kernel_launch(void* const* d_in, const int* in_sizes, int n_in,
                              void* d_out, int out_size, void* d_ws, size_t ws_size,
                              hipStream_t stream) {
    const float* x     = (const float*)d_in[0];
    const float* pre_h = (const float*)d_in[1];
    const float* Wf    = (const float*)d_in[2];
    const float* bf    = (const float*)d_in[3];
    const float* Wi    = (const float*)d_in[4];
    const float* bi    = (const float*)d_in[5];
    const float* Wh    = (const float*)d_in[6];
    const float* bh    = (const float*)d_in[7];
    float* out = (float*)d_out;

    char* ws = (char*)d_ws;
    const size_t FB = (size_t)M_TOT * DIM * sizeof(float);   // 64 MB
    float* fbuf  = (float*)(ws);
    float* vbuf  = (float*)(ws + FB);
    float* Ach   = (float*)(ws + 2 * FB);
    float* Bch   = (float*)(ws + 2 * FB + 524288);
    float* carry = (float*)(ws + 2 * FB + 1048576);

    gemm_gates<<<dim3(DIM / TN, M_TOT / TM), 256, 0, stream>>>(
        x, Wf, bf, Wi, bi, Wh, bh, fbuf, vbuf);
    scan_pass1<<<dim3(DIM / 256, NCHUNK, BATCH), 256, 0, stream>>>(fbuf, vbuf, Ach, Bch);
    scan_pass2<<<(BATCH * DIM) / 256, 256, 0, stream>>>(pre_h, Ach, Bch, carry);
    scan_pass3<<<dim3(DIM / 256, NCHUNK, BATCH), 256, 0, stream>>>(fbuf, vbuf, carry, out);
}

// Round 2
// 321.852 us; speedup vs baseline: 2.3766x; 2.3766x over previous
//
#include <hip/hip_runtime.h>
#include <hip/hip_bf16.h>

// Problem constants
#define BATCH 4
#define SEQ   8192
#define DIM   512
#define M_TOT (BATCH*SEQ)   // 32768
#define NCHUNK 128
#define CLEN   64           // SEQ / NCHUNK

// GEMM tiling
#define GBM 128
#define GBN 128
#define GBK 64              // i8 K per chunk (= one MFMA K)

typedef __attribute__((ext_vector_type(4))) int int4v;

__device__ __forceinline__ float sigmoidf_(float x) {
    return 1.0f / (1.0f + __expf(-x));
}
// g(x) = x>=0 ? x+0.5 : sigmoid(x)
__device__ __forceinline__ float gfun_(float x) {
    return (x >= 0.0f) ? (x + 0.5f) : sigmoidf_(x);
}

__device__ __forceinline__ void stage16(const void* g, void* lds) {
    __builtin_amdgcn_global_load_lds((const __attribute__((address_space(1))) void*)g,
                                     (__attribute__((address_space(3))) void*)lds,
                                     16, 0, 0);
}

// ---------------- quantization kernels ----------------
// x scale 2048 -> 16-bit, split into signed hi/lo i8 digits
__global__ __launch_bounds__(256) void quant_x(const float* __restrict__ x,
                                               char* __restrict__ xh, char* __restrict__ xl)
{
    const int t = blockIdx.x * 256 + threadIdx.x;        // one float4 per thread
    float4 v = ((const float4*)x)[t];
    float vals[4] = {v.x, v.y, v.z, v.w};
    char hs[4], ls[4];
    #pragma unroll
    for (int e = 0; e < 4; ++e) {
        float c = fminf(fmaxf(vals[e], -15.8f), 15.8f);
        int q = (int)rintf(c * 2048.0f);
        int hi = (q + 128) >> 8;
        int lo = q - (hi << 8);
        hs[e] = (char)hi; ls[e] = (char)lo;
    }
    char4 hv = {hs[0], hs[1], hs[2], hs[3]};
    char4 lv = {ls[0], ls[1], ls[2], ls[3]};
    *(char4*)&xh[(size_t)t * 4] = hv;
    *(char4*)&xl[(size_t)t * 4] = lv;
}

// W: read [k][n], write transposed [n][k], scale 65536, split hi/lo i8.
// 64x64 tiles, 3 gates in blockIdx.z
__global__ __launch_bounds__(256) void quant_wT(
    const float* __restrict__ Wf, const float* __restrict__ Wi, const float* __restrict__ Wh,
    char* __restrict__ wth, char* __restrict__ wtl)
{
    __shared__ float tile[64][65];
    const int g = blockIdx.z;
    const float* W = (g == 0) ? Wf : (g == 1) ? Wi : Wh;
    const int k0 = blockIdx.x * 64, n0 = blockIdx.y * 64;
    const int c = threadIdx.x & 63, r4 = threadIdx.x >> 6;
    #pragma unroll
    for (int p = 0; p < 16; ++p) {
        int r = p * 4 + r4;
        tile[r][c] = W[(size_t)(k0 + r) * DIM + n0 + c];
    }
    __syncthreads();
    const size_t gbase = (size_t)g * DIM * DIM;
    #pragma unroll
    for (int p = 0; p < 16; ++p) {
        int nr = p * 4 + r4;                 // local n
        float w = tile[c][nr];               // (k = k0+c, n = n0+nr)
        float cl = fminf(fmaxf(w, -0.49f), 0.49f);
        int q = (int)rintf(cl * 65536.0f);
        int hi = (q + 128) >> 8;
        int lo = q - (hi << 8);
        size_t o = gbase + (size_t)(n0 + nr) * DIM + k0 + c;
        wth[o] = (char)hi;
        wtl[o] = (char)lo;
    }
}

// ---------------- i8 MFMA GEMM ----------------
// grid.x = 12 (gate*4 + ntile), grid.y = 256 (m-tiles)
// k = (P2 * 65536 + P1 * 256) / (2048*65536) = P2/2048 + P1/524288
__global__ __launch_bounds__(256, 2) void gemm_i8(
    const char* __restrict__ xh, const char* __restrict__ xl,
    const char* __restrict__ wth, const char* __restrict__ wtl,
    const float* __restrict__ bfv, const float* __restrict__ biv, const float* __restrict__ bhv,
    float* __restrict__ fb, float* __restrict__ sib, float* __restrict__ ghb)
{
    __shared__ char sA[2][GBM][GBK];   // [digit][m][k], k XOR-swizzled
    __shared__ char sB[2][GBN][GBK];   // [digit][n][k]

    const int g  = blockIdx.x >> 2;
    const int n0 = (blockIdx.x & 3) * GBN;
    const int m0 = blockIdx.y * GBM;
    const int tid  = threadIdx.x;
    const int wave = tid >> 6;
    const int lane = tid & 63;
    const int wi = wave >> 1, wj = wave & 1;   // 2x2 waves of 64x64

    const char* wh_g = wth + (size_t)g * DIM * DIM;
    const char* wl_g = wtl + (size_t)g * DIM * DIM;

    int4v P2[4][4], P1[4][4];
    const int4v zero = {0, 0, 0, 0};
    #pragma unroll
    for (int i = 0; i < 4; ++i)
        #pragma unroll
        for (int j = 0; j < 4; ++j) { P2[i][j] = zero; P1[i][j] = zero; }

    for (int k0 = 0; k0 < DIM; k0 += GBK) {
        // ---- stage: 4 planes x 8 KB, wave-uniform LDS base + lane*16 ----
        #pragma unroll
        for (int it = 0; it < 2; ++it) {
            const int grp = it * 4 + wave;              // 0..7
            const int m   = grp * 16 + (lane >> 2);     // row within tile
            const int kb  = (lane & 3) * 16;            // byte within row
            const int ksw = kb ^ (((m >> 1) & 3) << 4); // global-side swizzle
            char* ldsA = &sA[0][grp * 16][0];           // base; +lane*16 by HW
            char* ldsB = &sB[0][grp * 16][0];
            char* ldsA1 = &sA[1][grp * 16][0];
            char* ldsB1 = &sB[1][grp * 16][0];
            stage16(xh  + (size_t)(m0 + m) * DIM + k0 + ksw, ldsA);
            stage16(xl  + (size_t)(m0 + m) * DIM + k0 + ksw, ldsA1);
            stage16(wh_g + (size_t)(n0 + m) * DIM + k0 + ksw, ldsB);
            stage16(wl_g + (size_t)(n0 + m) * DIM + k0 + ksw, ldsB1);
        }
        __syncthreads();

        // ---- fragments + MFMA ----
        const int kseg = (lane >> 4) * 16;
        int4v bhf[4], blf[4];
        #pragma unroll
        for (int j = 0; j < 4; ++j) {
            const int col = wj * 64 + j * 16 + (lane & 15);
            const int ks  = kseg ^ (((col >> 1) & 3) << 4);
            bhf[j] = *(const int4v*)&sB[0][col][ks];
            blf[j] = *(const int4v*)&sB[1][col][ks];
        }
        #pragma unroll
        for (int i = 0; i < 4; ++i) {
            const int row = wi * 64 + i * 16 + (lane & 15);
            const int ks  = kseg ^ (((row >> 1) & 3) << 4);
            int4v ahf = *(const int4v*)&sA[0][row][ks];
            int4v alf = *(const int4v*)&sA[1][row][ks];
            #pragma unroll
            for (int j = 0; j < 4; ++j) {
                P2[i][j] = __builtin_amdgcn_mfma_i32_16x16x64_i8(ahf, bhf[j], P2[i][j], 0, 0, 0);
                P1[i][j] = __builtin_amdgcn_mfma_i32_16x16x64_i8(ahf, blf[j], P1[i][j], 0, 0, 0);
                P1[i][j] = __builtin_amdgcn_mfma_i32_16x16x64_i8(alf, bhf[j], P1[i][j], 0, 0, 0);
            }
        }
        __syncthreads();
    }

    // ---- epilogue: bias + activation, write one of f/si/gh ----
    const float c2 = 1.0f / 2048.0f;
    const float c1 = 1.0f / 524288.0f;
    const float* bias = (g == 0) ? bfv : (g == 1) ? biv : bhv;
    float* outp = (g == 0) ? fb : (g == 1) ? sib : ghb;
    #pragma unroll
    for (int i = 0; i < 4; ++i) {
        #pragma unroll
        for (int j = 0; j < 4; ++j) {
            const int col = n0 + wj * 64 + j * 16 + (lane & 15);
            const float bv = bias[col];
            #pragma unroll
            for (int r = 0; r < 4; ++r) {
                const int row = m0 + wi * 64 + i * 16 + (lane >> 4) * 4 + r;
                float kv = (float)P2[i][j][r] * c2 + (float)P1[i][j][r] * c1 + bv;
                float o = (g == 2) ? gfun_(kv) : sigmoidf_(kv);
                outp[(size_t)row * DIM + col] = o;
            }
        }
    }
}

// ---------------- scan kernels ----------------
__global__ __launch_bounds__(256) void scan_pass1(
    const float* __restrict__ fb, const float* __restrict__ sib, const float* __restrict__ ghb,
    float* __restrict__ Ach, float* __restrict__ Bch)
{
    const int d = blockIdx.x * 256 + threadIdx.x;
    const int c = blockIdx.y;
    const int b = blockIdx.z;
    float A = 1.0f, Bacc = 0.0f;
    size_t base = ((size_t)(b * SEQ + c * CLEN)) * DIM + d;
    #pragma unroll 4
    for (int t = 0; t < CLEN; ++t) {
        float f = fb[base + (size_t)t * DIM];
        float v = sib[base + (size_t)t * DIM] * ghb[base + (size_t)t * DIM];
        Bacc = fmaf(f, Bacc, v);
        A *= f;
    }
    const int idx = (b * NCHUNK + c) * DIM + d;
    Ach[idx] = A;
    Bch[idx] = Bacc;
}

__global__ __launch_bounds__(256) void scan_pass2(
    const float* __restrict__ pre_h,
    const float* __restrict__ Ach, const float* __restrict__ Bch,
    float* __restrict__ carry)
{
    const int gidx = blockIdx.x * 256 + threadIdx.x;  // 0..2047
    const int b = gidx >> 9;
    const int d = gidx & (DIM - 1);
    float h = gfun_(pre_h[b * DIM + d]);
    for (int c = 0; c < NCHUNK; ++c) {
        const int idx = (b * NCHUNK + c) * DIM + d;
        carry[idx] = h;
        h = fmaf(Ach[idx], h, Bch[idx]);
    }
}

__global__ __launch_bounds__(256) void scan_pass3(
    const float* __restrict__ fb, const float* __restrict__ sib, const float* __restrict__ ghb,
    const float* __restrict__ carry, float* __restrict__ out)
{
    const int d = blockIdx.x * 256 + threadIdx.x;
    const int c = blockIdx.y;
    const int b = blockIdx.z;
    float h = carry[(b * NCHUNK + c) * DIM + d];
    size_t base = ((size_t)(b * SEQ + c * CLEN)) * DIM + d;
    #pragma unroll 4
    for (int t = 0; t < CLEN; ++t) {
        float f = fb[base + (size_t)t * DIM];
        float v = sib[base + (size_t)t * DIM] * ghb[base + (size_t)t * DIM];
        h = fmaf(f, h, v);
        out[base + (size_t)t * DIM] = h;
    }
}

extern "C" void kernel_launch(void* const* d_in, const int* in_sizes, int n_in,
                              void* d_out, int out_size, void* d_ws, size_t ws_size,
                              hipStream_t stream) {
    const float* x     = (const float*)d_in[0];
    const float* pre_h = (const float*)d_in[1];
    const float* Wf    = (const float*)d_in[2];
    const float* bf    = (const float*)d_in[3];
    const float* Wi    = (const float*)d_in[4];
    const float* bi    = (const float*)d_in[5];
    const float* Wh    = (const float*)d_in[6];
    const float* bh    = (const float*)d_in[7];
    float* out = (float*)d_out;

    char* ws = (char*)d_ws;
    const size_t XQ = (size_t)M_TOT * DIM;            // 16 MB (i8 plane)
    const size_t WQ = (size_t)3 * DIM * DIM;          // 768 KB (i8, 3 gates)
    const size_t FB = (size_t)M_TOT * DIM * sizeof(float); // 64 MB

    char*  xh  = ws;
    char*  xl  = ws + XQ;
    char*  wth = ws + 2 * XQ;
    char*  wtl = ws + 2 * XQ + WQ;
    float* fbuf  = (float*)(ws + 2 * XQ + 2 * WQ);
    float* sibuf = (float*)((char*)fbuf + FB);
    float* ghbuf = (float*)((char*)sibuf + FB);
    float* Ach   = (float*)((char*)ghbuf + FB);
    float* Bch   = (float*)((char*)Ach + (size_t)BATCH * NCHUNK * DIM * 4);
    float* carry = (float*)((char*)Bch + (size_t)BATCH * NCHUNK * DIM * 4);

    quant_x<<<(M_TOT * DIM / 4) / 256, 256, 0, stream>>>(x, xh, xl);
    quant_wT<<<dim3(8, 8, 3), 256, 0, stream>>>(Wf, Wi, Wh, wth, wtl);
    gemm_i8<<<dim3(12, M_TOT / GBM), 256, 0, stream>>>(
        xh, xl, wth, wtl, bf, bi, bh, fbuf, sibuf, ghbuf);
    scan_pass1<<<dim3(DIM / 256, NCHUNK, BATCH), 256, 0, stream>>>(fbuf, sibuf, ghbuf, Ach, Bch);
    scan_pass2<<<(BATCH * DIM) / 256, 256, 0, stream>>>(pre_h, Ach, Bch, carry);
    scan_pass3<<<dim3(DIM / 256, NCHUNK, BATCH), 256, 0, stream>>>(fbuf, sibuf, ghbuf, carry, out);
}